// Round 13
// baseline (162.195 us; speedup 1.0000x reference)
//
#include <hip/hip_runtime.h>

// StrictLowerTriQSM: f_{i+1} = a_i @ f_i + outer(q_i, x_i), y_i = p_i @ f_i
// N=500000, M=8, K=16. Blocked associative scan.
// Round 13: champion (r8/r12) structure with NC=32768/CH=16 and DOUBLE
// buffering (1-ahead counted vmcnt) -> 22.5/24.6 KB LDS per block ->
// 28/24 waves/CU (was 16). Lane maps and LDS layouts unchanged.
// ws-guarded fallbacks: 32768 (25.6 MB) -> 16384 (12.8 MB) -> 8192.

#define NTOT 500000

#define AS1(p) ((const __attribute__((address_space(1))) void*)(p))
#define AS3(p) ((__attribute__((address_space(3))) void*)(p))
#define GLOAD_LDS16(gp, lp) __builtin_amdgcn_global_load_lds(AS1(gp), AS3(lp), 16, 0, 0)
#define GLOAD_LDS4(gp, lp)  __builtin_amdgcn_global_load_lds(AS1(gp), AS3(lp), 4, 0, 0)
#define WAIT_VM(n) asm volatile("s_waitcnt vmcnt(" #n ")" ::: "memory")

static __device__ __forceinline__ int iminc(int a, int b) { return a < b ? a : b; }

template<int NC> struct P {
  static constexpr int CH   = 524288 / NC;               // 32768->16, 16384->32, 8192->64
  static constexpr int NST  = CH / 2;                    // stages (2 elems each)
  static constexpr int NG   = NC / 64;                   // groups
  static constexpr int NS   = NG / 64;                   // supers
  static constexpr int AGGA = 0;                         // NC*64
  static constexpr int AGGB = NC * 64;                   // NC*128
  static constexpr int GAGA = NC * 192;                  // NG*64
  static constexpr int GAGB = NC * 192 + NG * 64;        // NG*128
  static constexpr int SGA  = NC * 192 + NG * 192;       // NS*64
  static constexpr int SGB  = NC * 192 + NG * 192 + NS * 64; // NS*128
  static constexpr size_t BYTES = (size_t)(NC * 192 + NG * 192 + NS * 192) * 4u;
};

// ---------------- Phase 1: per-chunk aggregates (A_blk, B_blk) -------------
// 4 chunks/wave: g = lane>>4 owns chunk wave*4+g; ll = lane&15 = B column;
// lanes ll>=8 additionally carry A column (ll-8). Per element every lane
// computes both the B and A matvecs (shared a rows).
// LDS buffer (floats): a[2 slots][4 ch][64] | q[4][2][8] @512 | x @576
// (layout (g,e,k) -> 576 + (g>>1)*64 + (g&1)*32 + e*16 + k). BUF=704, x2.
#define K1_COMP(E, VBS, VAS, VBD, VAD) do {                                  \
    const float xk_ = xgb[(E) * 16];                                         \
    const float4 q0_ = *(const float4*)(qgb + (E) * 8);                      \
    const float4 q1_ = *(const float4*)(qgb + (E) * 8 + 4);                  \
    const float qv_[8] = {q0_.x,q0_.y,q0_.z,q0_.w,q1_.x,q1_.y,q1_.z,q1_.w};  \
    _Pragma("unroll") for (int mm = 0; mm < 8; ++mm) {                       \
      const float4 r0_ = *(const float4*)(agb + (E) * 256 + mm * 8);         \
      const float4 r1_ = *(const float4*)(agb + (E) * 256 + mm * 8 + 4);     \
      VBD[mm] = qv_[mm] * xk_                                                \
              + r0_.x*VBS[0] + r0_.y*VBS[1] + r0_.z*VBS[2] + r0_.w*VBS[3]    \
              + r1_.x*VBS[4] + r1_.y*VBS[5] + r1_.z*VBS[6] + r1_.w*VBS[7];   \
      VAD[mm] = r0_.x*VAS[0] + r0_.y*VAS[1] + r0_.z*VAS[2] + r0_.w*VAS[3]    \
              + r1_.x*VAS[4] + r1_.y*VAS[5] + r1_.z*VAS[6] + r1_.w*VAS[7];   \
    }                                                                        \
  } while (0)

template<int NC>
__global__ __launch_bounds__(256, 4) void k1_aggregate(
    const float* __restrict__ q, const float* __restrict__ a,
    const float* __restrict__ x, float* __restrict__ ws)
{
  using PP = P<NC>;
  constexpr int CH = PP::CH, NST = PP::NST;
  __shared__ float sm[4 * 2 * 704];   // 22528 B
  const int wv   = (int)(threadIdx.x >> 6);
  const int wave = blockIdx.x * 4 + wv;
  const int lane = (int)(threadIdx.x & 63);
  const int g    = lane >> 4;
  const int ll   = lane & 15;
  const int c    = wave * 4 + g;
  const bool hasA = ll >= 8;
  const int acol  = ll & 7;

  const int cb = wave * 4;
  float* b0 = sm + wv * 1408;
  float* b1 = b0 + 704;

  const int goff = g * 64;
  const int qoff = 512 + g * 16;
  const int xoff = 576 + (g >> 1) * 64 + (g & 1) * 32 + ll;

  float vB0[8], vA0[8], vB1[8], vA1[8];
#pragma unroll
  for (int m = 0; m < 8; ++m) { vB0[m] = 0.f; vA0[m] = 0.f; }
  if (hasA) vA0[acol] = 1.f;

  const int gl = lane >> 4, ql = lane & 15;
  auto stage = [&](int ss, float* lb) {          // 5 loads
    const int base = cb * CH + ss * 2;
    GLOAD_LDS16(a + (size_t)iminc(base + gl * CH,     NTOT - 1) * 64u + ql * 4, lb);
    GLOAD_LDS16(a + (size_t)iminc(base + gl * CH + 1, NTOT - 1) * 64u + ql * 4, lb + 256);
    GLOAD_LDS4 (q + (size_t)iminc(base + (lane >> 4) * CH + ((lane >> 3) & 1), NTOT - 1) * 8u  + (lane & 7),  lb + 512);
    GLOAD_LDS4 (x + (size_t)iminc(base + (lane >> 5) * CH + ((lane >> 4) & 1), NTOT - 1) * 16u + (lane & 15), lb + 576);
    GLOAD_LDS4 (x + (size_t)iminc(base + (2 + (lane >> 5)) * CH + ((lane >> 4) & 1), NTOT - 1) * 16u + (lane & 15), lb + 640);
  };

  stage(0, b0);
#pragma unroll 1
  for (int ss = 0; ss < NST; ++ss) {
    float* cur = (ss & 1) ? b1 : b0;
    float* nxt = (ss & 1) ? b0 : b1;
    if (ss + 1 < NST) { stage(ss + 1, nxt); WAIT_VM(5); }
    else              { WAIT_VM(0); }
    const float* agb = cur + goff;
    const float* qgb = cur + qoff;
    const float* xgb = cur + xoff;
    K1_COMP(0, vB0, vA0, vB1, vA1);
    K1_COMP(1, vB1, vA1, vB0, vA0);
  }

  {
    float* dst = ws + PP::AGGB + (size_t)c * 128u + (size_t)ll * 8u;
#pragma unroll
    for (int m = 0; m < 8; ++m) dst[m] = vB0[m];
  }
  if (hasA) {
    float* dst = ws + PP::AGGA + (size_t)c * 64u + (size_t)acol * 8u;
#pragma unroll
    for (int m = 0; m < 8; ++m) dst[m] = vA0[m];
  }
}

// ---------- Phase 2 generic: serial scan of 64 items per block -------------
// LV=0: chunk aggs within a group -> GAG*. LV=1: group aggs within a super
// -> SG*. IN-PLACE: item slot <- segment-local EXCLUSIVE prefix.
template<int NC, int LV>
__global__ __launch_bounds__(64) void k2scan(float* __restrict__ ws)
{
  using PP = P<NC>;
  constexpr int OFFAIN  = (LV == 0) ? PP::AGGA : PP::GAGA;
  constexpr int OFFBIN  = (LV == 0) ? PP::AGGB : PP::GAGB;
  constexpr int OFFAOUT = (LV == 0) ? PP::GAGA : PP::SGA;
  constexpr int OFFBOUT = (LV == 0) ? PP::GAGB : PP::SGB;
  __shared__ float sA[64 * 64];   // 16 KiB
  const int g    = blockIdx.x;
  const int lane = (int)(threadIdx.x & 63);
  const bool isB = lane < 16;
  const bool isA = (lane >= 16) && (lane < 24);
  const int bcol = lane & 15;
  const int acol = (lane - 16) & 7;

#pragma unroll 1
  for (int t = 0; t < 16; ++t)
    GLOAD_LDS16(ws + OFFAIN + (size_t)g * 4096u + t * 256 + lane * 4, sA + t * 256);

  float v[8];
#pragma unroll
  for (int m = 0; m < 8; ++m) v[m] = 0.f;
  if (isA) v[acol] = 1.f;

  float4 nb0, nb1;
  {
    const float* s = ws + OFFBIN + (size_t)(g * 64) * 128u + (size_t)bcol * 8u;
    nb0 = *(const float4*)s; nb1 = *(const float4*)(s + 4);
  }
  WAIT_VM(0);

#pragma unroll 1
  for (int j = 0; j < 64; ++j) {
    const int c = g * 64 + j;
    float bB[8] = {nb0.x, nb0.y, nb0.z, nb0.w, nb1.x, nb1.y, nb1.z, nb1.w};
    if (j + 1 < 64) {
      const float* s = ws + OFFBIN + (size_t)(c + 1) * 128u + (size_t)bcol * 8u;
      nb0 = *(const float4*)s; nb1 = *(const float4*)(s + 4);
    }
    if (isB) {
      float* dst = ws + OFFBIN + (size_t)c * 128u + (size_t)bcol * 8u;
#pragma unroll
      for (int m = 0; m < 8; ++m) dst[m] = v[m];
    } else if (isA) {
      float* dst = ws + OFFAIN + (size_t)c * 64u + (size_t)acol * 8u;
#pragma unroll
      for (int m = 0; m < 8; ++m) dst[m] = v[m];
    }
    const float* Aj = sA + j * 64;
    float nv[8];
#pragma unroll
    for (int m = 0; m < 8; ++m) nv[m] = 0.f;
#pragma unroll
    for (int t = 0; t < 8; ++t) {
      float4 col0 = *(const float4*)(Aj + t * 8);
      float4 col1 = *(const float4*)(Aj + t * 8 + 4);
      nv[0] += col0.x * v[t]; nv[1] += col0.y * v[t];
      nv[2] += col0.z * v[t]; nv[3] += col0.w * v[t];
      nv[4] += col1.x * v[t]; nv[5] += col1.y * v[t];
      nv[6] += col1.z * v[t]; nv[7] += col1.w * v[t];
    }
    if (isB) {
#pragma unroll
      for (int m = 0; m < 8; ++m) nv[m] += bB[m];
    }
#pragma unroll
    for (int m = 0; m < 8; ++m) v[m] = nv[m];
  }

  if (isB) {
    float* dst = ws + OFFBOUT + (size_t)g * 128u + (size_t)bcol * 8u;
#pragma unroll
    for (int m = 0; m < 8; ++m) dst[m] = v[m];
  } else if (isA) {
    float* dst = ws + OFFAOUT + (size_t)g * 64u + (size_t)acol * 8u;
#pragma unroll
    for (int m = 0; m < 8; ++m) dst[m] = v[m];
  }
}

// ---------- Phase 2c: single-wave scan over the NS super aggregates --------
// IN-PLACE on SGB: slot <- global-exclusive B prefix. SGA read-only.
template<int NC>
__global__ __launch_bounds__(64) void k2c_topscan(float* __restrict__ ws)
{
  using PP = P<NC>;
  const int lane = (int)(threadIdx.x & 63);
  const bool isB = lane < 16;
  const int bcol = lane & 15;

  float v[8];
#pragma unroll
  for (int m = 0; m < 8; ++m) v[m] = 0.f;

#pragma unroll 1
  for (int j = 0; j < PP::NS; ++j) {
    float bB[8];
    if (isB) {
      const float* s = ws + PP::SGB + (size_t)j * 128u + (size_t)bcol * 8u;
#pragma unroll
      for (int m = 0; m < 8; ++m) bB[m] = s[m];
      float* dst = ws + PP::SGB + (size_t)j * 128u + (size_t)bcol * 8u;
#pragma unroll
      for (int m = 0; m < 8; ++m) dst[m] = v[m];
    }
    const float* Aj = ws + PP::SGA + (size_t)j * 64u;
    float nv[8];
#pragma unroll
    for (int m = 0; m < 8; ++m) nv[m] = 0.f;
#pragma unroll
    for (int t = 0; t < 8; ++t) {
      float4 col0 = *(const float4*)(Aj + t * 8);
      float4 col1 = *(const float4*)(Aj + t * 8 + 4);
      nv[0] += col0.x * v[t]; nv[1] += col0.y * v[t];
      nv[2] += col0.z * v[t]; nv[3] += col0.w * v[t];
      nv[4] += col1.x * v[t]; nv[5] += col1.y * v[t];
      nv[6] += col1.z * v[t]; nv[7] += col1.w * v[t];
    }
    if (isB) {
#pragma unroll
      for (int m = 0; m < 8; ++m) nv[m] += bB[m];
    }
#pragma unroll
    for (int m = 0; m < 8; ++m) v[m] = nv[m];
  }
}

// ---------- Phase 3: replay each chunk from its carry, emit y --------------
// 4 chunks/wave, k = lane&15 = f column; all 64 lanes compute + store.
// f-init composes 3 levels: f0 = prefB_c + prefA_c@(gB_gr + gA_gr@sB_s).
// Buffer: a[2][4][64] | q @512 | p @576 | x @640. BUF=768, x2.
#define K3_COMP(E, FS, FD) do {                                              \
    const float xk_ = xgb[(E) * 16];                                         \
    const float4 q0_ = *(const float4*)(qgb + (E) * 8);                      \
    const float4 q1_ = *(const float4*)(qgb + (E) * 8 + 4);                  \
    const float4 p0_ = *(const float4*)(pgb + (E) * 8);                      \
    const float4 p1_ = *(const float4*)(pgb + (E) * 8 + 4);                  \
    const float y_ = p0_.x*FS[0] + p0_.y*FS[1] + p0_.z*FS[2] + p0_.w*FS[3]   \
                   + p1_.x*FS[4] + p1_.y*FS[5] + p1_.z*FS[6] + p1_.w*FS[7];  \
    const int i_ = c * CH + ss * 2 + (E);                                    \
    if (i_ < NTOT) out[(size_t)i_ * 16u + k] = y_;                           \
    const float qv_[8] = {q0_.x,q0_.y,q0_.z,q0_.w,q1_.x,q1_.y,q1_.z,q1_.w};  \
    _Pragma("unroll") for (int mm = 0; mm < 8; ++mm) {                       \
      const float4 r0_ = *(const float4*)(agb + (E) * 256 + mm * 8);         \
      const float4 r1_ = *(const float4*)(agb + (E) * 256 + mm * 8 + 4);     \
      FD[mm] = qv_[mm] * xk_                                                 \
             + r0_.x*FS[0] + r0_.y*FS[1] + r0_.z*FS[2] + r0_.w*FS[3]         \
             + r1_.x*FS[4] + r1_.y*FS[5] + r1_.z*FS[6] + r1_.w*FS[7];        \
    }                                                                        \
  } while (0)

template<int NC>
__global__ __launch_bounds__(256, 4) void k3_output(
    const float* __restrict__ p, const float* __restrict__ q,
    const float* __restrict__ a, const float* __restrict__ x,
    const float* __restrict__ ws, float* __restrict__ out)
{
  using PP = P<NC>;
  constexpr int CH = PP::CH, NST = PP::NST;
  __shared__ float sm3[4 * 2 * 768];  // 24576 B
  const int wv   = (int)(threadIdx.x >> 6);
  const int wave = blockIdx.x * 4 + wv;
  const int lane = (int)(threadIdx.x & 63);
  const int g    = lane >> 4;
  const int k    = lane & 15;
  const int c    = wave * 4 + g;
  const int gr   = c >> 6;
  const int sidx = gr >> 6;

  const int cb = wave * 4;
  float* b0 = sm3 + wv * 1536;
  float* b1 = b0 + 768;

  const int goff = g * 64;
  const int qoff = 512 + g * 16;
  const int poff = 576 + g * 16;
  const int xoff = 640 + (g >> 1) * 64 + (g & 1) * 32 + k;

  auto stage = [&](int ss, float* lb) {          // 6 loads
    const int base = cb * CH + ss * 2;
    GLOAD_LDS16(a + (size_t)iminc(base + (lane >> 4) * CH,     NTOT - 1) * 64u + (lane & 15) * 4, lb);
    GLOAD_LDS16(a + (size_t)iminc(base + (lane >> 4) * CH + 1, NTOT - 1) * 64u + (lane & 15) * 4, lb + 256);
    GLOAD_LDS4 (q + (size_t)iminc(base + (lane >> 4) * CH + ((lane >> 3) & 1), NTOT - 1) * 8u  + (lane & 7),  lb + 512);
    GLOAD_LDS4 (p + (size_t)iminc(base + (lane >> 4) * CH + ((lane >> 3) & 1), NTOT - 1) * 8u  + (lane & 7),  lb + 576);
    GLOAD_LDS4 (x + (size_t)iminc(base + (lane >> 5) * CH + ((lane >> 4) & 1), NTOT - 1) * 16u + (lane & 15), lb + 640);
    GLOAD_LDS4 (x + (size_t)iminc(base + (2 + (lane >> 5)) * CH + ((lane >> 4) & 1), NTOT - 1) * 16u + (lane & 15), lb + 704);
  };

  // f-init FIRST (plain global loads; compiler-managed waits) so the counted
  // vmcnt staging pipeline below starts from a drained state.
  // t1 = gB_gr[:,k] + gA_gr @ sB_s[:,k]; f0 = prefB_c[:,k] + prefA_c @ t1
  const float* __restrict__ sBc = ws + PP::SGB  + (size_t)sidx * 128u + (size_t)k * 8u;
  const float* __restrict__ gBc = ws + PP::GAGB + (size_t)gr   * 128u + (size_t)k * 8u;
  const float* __restrict__ gA  = ws + PP::GAGA + (size_t)gr   * 64u;
  const float* __restrict__ pA  = ws + PP::AGGA + (size_t)c    * 64u;
  const float* __restrict__ lBc = ws + PP::AGGB + (size_t)c    * 128u + (size_t)k * 8u;
  float t1[8];
#pragma unroll
  for (int m = 0; m < 8; ++m) t1[m] = gBc[m];
#pragma unroll
  for (int t = 0; t < 8; ++t) {
    float4 c0 = *(const float4*)(gA + t * 8);
    float4 c1 = *(const float4*)(gA + t * 8 + 4);
    const float st = sBc[t];
    t1[0] += c0.x * st; t1[1] += c0.y * st; t1[2] += c0.z * st; t1[3] += c0.w * st;
    t1[4] += c1.x * st; t1[5] += c1.y * st; t1[6] += c1.z * st; t1[7] += c1.w * st;
  }
  float f0[8], f1[8];
#pragma unroll
  for (int m = 0; m < 8; ++m) f0[m] = lBc[m];
#pragma unroll
  for (int t = 0; t < 8; ++t) {
    float4 c0 = *(const float4*)(pA + t * 8);
    float4 c1 = *(const float4*)(pA + t * 8 + 4);
    const float gt = t1[t];
    f0[0] += c0.x * gt; f0[1] += c0.y * gt; f0[2] += c0.z * gt; f0[3] += c0.w * gt;
    f0[4] += c1.x * gt; f0[5] += c1.y * gt; f0[6] += c1.z * gt; f0[7] += c1.w * gt;
  }
  asm volatile("" ::: "memory");   // keep staging below the f-init loads

  stage(0, b0);
#pragma unroll 1
  for (int ss = 0; ss < NST; ++ss) {
    float* cur = (ss & 1) ? b1 : b0;
    float* nxt = (ss & 1) ? b0 : b1;
    if (ss + 1 < NST) { stage(ss + 1, nxt); WAIT_VM(6); }
    else              { WAIT_VM(0); }
    const float* agb = cur + goff;
    const float* qgb = cur + qoff;
    const float* pgb = cur + poff;
    const float* xgb = cur + xoff;
    K3_COMP(0, f0, f1);
    K3_COMP(1, f1, f0);
  }
}

template<int NC>
static void launch_all(const float* p, const float* q, const float* a,
                       const float* x, float* out, float* ws, hipStream_t stream)
{
  using PP = P<NC>;
  hipLaunchKernelGGL(HIP_KERNEL_NAME(k1_aggregate<NC>), dim3(NC / 16), dim3(256), 0, stream, q, a, x, ws);
  hipLaunchKernelGGL(HIP_KERNEL_NAME(k2scan<NC, 0>),    dim3(PP::NG),  dim3(64),  0, stream, ws);
  hipLaunchKernelGGL(HIP_KERNEL_NAME(k2scan<NC, 1>),    dim3(PP::NS),  dim3(64),  0, stream, ws);
  hipLaunchKernelGGL(HIP_KERNEL_NAME(k2c_topscan<NC>),  dim3(1),       dim3(64),  0, stream, ws);
  hipLaunchKernelGGL(HIP_KERNEL_NAME(k3_output<NC>),    dim3(NC / 16), dim3(256), 0, stream, p, q, a, x, ws, out);
}

extern "C" void kernel_launch(void* const* d_in, const int* in_sizes, int n_in,
                              void* d_out, int out_size, void* d_ws, size_t ws_size,
                              hipStream_t stream)
{
  const float* p = (const float*)d_in[0];
  const float* q = (const float*)d_in[1];
  const float* a = (const float*)d_in[2];
  const float* x = (const float*)d_in[3];
  float* out = (float*)d_out;
  float* ws  = (float*)d_ws;

  if (ws_size >= P<32768>::BYTES) {
    launch_all<32768>(p, q, a, x, out, ws, stream);   // 25.6 MB, 28 waves/CU
  } else if (ws_size >= P<16384>::BYTES) {
    launch_all<16384>(p, q, a, x, out, ws, stream);   // 12.8 MB path
  } else {
    launch_all<8192>(p, q, a, x, out, ws, stream);    // 6.4 MB fallback
  }
}

// Round 14
// 157.331 us; speedup vs baseline: 1.0309x; 1.0309x over previous
//
#include <hip/hip_runtime.h>

// StrictLowerTriQSM: f_{i+1} = a_i @ f_i + outer(q_i, x_i), y_i = p_i @ f_i
// N=500000, M=8, K=16. Blocked associative scan.
// Round 14 = champion (r8/r12) verbatim, 157.8 us: NCHUNK=16384/CHUNK=32,
// 4 chunks/wave, G=2 triple-buffered staging, 3-level scan, ws-guarded
// fallback to NCHUNK=8192. r13 falsified the occupancy lever (HW caps
// resident waves); this decomposition's structural plateau.

#define NTOT 500000

#define AS1(p) ((const __attribute__((address_space(1))) void*)(p))
#define AS3(p) ((__attribute__((address_space(3))) void*)(p))
#define GLOAD_LDS16(gp, lp) __builtin_amdgcn_global_load_lds(AS1(gp), AS3(lp), 16, 0, 0)
#define GLOAD_LDS4(gp, lp)  __builtin_amdgcn_global_load_lds(AS1(gp), AS3(lp), 4, 0, 0)
#define WAIT_VM(n) asm volatile("s_waitcnt vmcnt(" #n ")" ::: "memory")

static __device__ __forceinline__ int iminc(int a, int b) { return a < b ? a : b; }

template<int NC> struct P {
  static constexpr int CH   = (NC == 16384) ? 32 : 64;   // elements per chunk
  static constexpr int NST  = CH / 2;                    // stages (G=2)
  static constexpr int NG   = NC / 64;                   // groups
  static constexpr int NS   = NG / 64;                   // supers
  static constexpr int AGGA = 0;                         // NC*64
  static constexpr int AGGB = NC * 64;                   // NC*128
  static constexpr int GAGA = NC * 192;                  // NG*64
  static constexpr int GAGB = NC * 192 + NG * 64;        // NG*128
  static constexpr int SGA  = NC * 192 + NG * 192;       // NS*64
  static constexpr int SGB  = NC * 192 + NG * 192 + NS * 64; // NS*128
  static constexpr size_t BYTES = (size_t)(NC * 192 + NG * 192 + NS * 192) * 4u;
};

// ---------------- Phase 1: per-chunk aggregates (A_blk, B_blk) -------------
// 4 chunks/wave: g = lane>>4 owns chunk wave*4+g; ll = lane&15 = B column;
// lanes ll>=8 additionally carry A column (ll-8). Per element every lane
// computes both the B and A matvecs (shared a rows).
// LDS buffer (floats): a[2 slots][4 ch][64] | q[4][2][8] @512 | x @576
// (layout (g,e,k) -> 576 + (g>>1)*64 + (g&1)*32 + e*16 + k). BUF=704, x3.
#define K1_COMP(E, VBS, VAS, VBD, VAD) do {                                  \
    const float xk_ = xgb[(E) * 16];                                         \
    const float4 q0_ = *(const float4*)(qgb + (E) * 8);                      \
    const float4 q1_ = *(const float4*)(qgb + (E) * 8 + 4);                  \
    const float qv_[8] = {q0_.x,q0_.y,q0_.z,q0_.w,q1_.x,q1_.y,q1_.z,q1_.w};  \
    _Pragma("unroll") for (int mm = 0; mm < 8; ++mm) {                       \
      const float4 r0_ = *(const float4*)(agb + (E) * 256 + mm * 8);         \
      const float4 r1_ = *(const float4*)(agb + (E) * 256 + mm * 8 + 4);     \
      VBD[mm] = qv_[mm] * xk_                                                \
              + r0_.x*VBS[0] + r0_.y*VBS[1] + r0_.z*VBS[2] + r0_.w*VBS[3]    \
              + r1_.x*VBS[4] + r1_.y*VBS[5] + r1_.z*VBS[6] + r1_.w*VBS[7];   \
      VAD[mm] = r0_.x*VAS[0] + r0_.y*VAS[1] + r0_.z*VAS[2] + r0_.w*VAS[3]    \
              + r1_.x*VAS[4] + r1_.y*VAS[5] + r1_.z*VAS[6] + r1_.w*VAS[7];   \
    }                                                                        \
  } while (0)

template<int NC>
__global__ __launch_bounds__(256, 4) void k1_aggregate(
    const float* __restrict__ q, const float* __restrict__ a,
    const float* __restrict__ x, float* __restrict__ ws)
{
  using PP = P<NC>;
  constexpr int CH = PP::CH, NST = PP::NST;
  __shared__ float sm[4 * 3 * 704];   // 33792 B
  const int wv   = (int)(threadIdx.x >> 6);
  const int wave = blockIdx.x * 4 + wv;
  const int lane = (int)(threadIdx.x & 63);
  const int g    = lane >> 4;
  const int ll   = lane & 15;
  const int c    = wave * 4 + g;
  const bool hasA = ll >= 8;
  const int acol  = ll & 7;

  const int cb = wave * 4;
  float* b0 = sm + wv * 2112;
  float* b1 = b0 + 704;
  float* b2 = b0 + 1408;

  const int goff = g * 64;
  const int qoff = 512 + g * 16;
  const int xoff = 576 + (g >> 1) * 64 + (g & 1) * 32 + ll;

  float vB0[8], vA0[8], vB1[8], vA1[8];
#pragma unroll
  for (int m = 0; m < 8; ++m) { vB0[m] = 0.f; vA0[m] = 0.f; }
  if (hasA) vA0[acol] = 1.f;

  const int gl = lane >> 4, ql = lane & 15;
  auto stage = [&](int ss, float* lb) {          // 5 loads
    const int base = cb * CH + ss * 2;
    GLOAD_LDS16(a + (size_t)iminc(base + gl * CH,     NTOT - 1) * 64u + ql * 4, lb);
    GLOAD_LDS16(a + (size_t)iminc(base + gl * CH + 1, NTOT - 1) * 64u + ql * 4, lb + 256);
    GLOAD_LDS4 (q + (size_t)iminc(base + (lane >> 4) * CH + ((lane >> 3) & 1), NTOT - 1) * 8u  + (lane & 7),  lb + 512);
    GLOAD_LDS4 (x + (size_t)iminc(base + (lane >> 5) * CH + ((lane >> 4) & 1), NTOT - 1) * 16u + (lane & 15), lb + 576);
    GLOAD_LDS4 (x + (size_t)iminc(base + (2 + (lane >> 5)) * CH + ((lane >> 4) & 1), NTOT - 1) * 16u + (lane & 15), lb + 640);
  };

  stage(0, b0);
  stage(1, b1);
#pragma unroll 1
  for (int ss = 0; ss < NST; ++ss) {
    float* lb = b0;
    if (ss + 2 < NST) {
      stage(ss + 2, b2);
      WAIT_VM(10);
    } else if (ss + 1 < NST) {
      WAIT_VM(5);
    } else {
      WAIT_VM(0);
    }
    const float* agb = lb + goff;
    const float* qgb = lb + qoff;
    const float* xgb = lb + xoff;
    K1_COMP(0, vB0, vA0, vB1, vA1);
    K1_COMP(1, vB1, vA1, vB0, vA0);
    float* t = b0; b0 = b1; b1 = b2; b2 = t;
  }

  {
    float* dst = ws + PP::AGGB + (size_t)c * 128u + (size_t)ll * 8u;
#pragma unroll
    for (int m = 0; m < 8; ++m) dst[m] = vB0[m];
  }
  if (hasA) {
    float* dst = ws + PP::AGGA + (size_t)c * 64u + (size_t)acol * 8u;
#pragma unroll
    for (int m = 0; m < 8; ++m) dst[m] = vA0[m];
  }
}

// ---------- Phase 2 generic: serial scan of 64 items per block -------------
// LV=0: scan chunk aggregates within a group (in: AGG*, agg out: GAG*).
// LV=1: scan group aggregates within a super (in: GAG*, agg out: SG*).
// IN-PLACE: item slot <- segment-local EXCLUSIVE prefix.
template<int NC, int LV>
__global__ __launch_bounds__(64) void k2scan(float* __restrict__ ws)
{
  using PP = P<NC>;
  constexpr int OFFAIN  = (LV == 0) ? PP::AGGA : PP::GAGA;
  constexpr int OFFBIN  = (LV == 0) ? PP::AGGB : PP::GAGB;
  constexpr int OFFAOUT = (LV == 0) ? PP::GAGA : PP::SGA;
  constexpr int OFFBOUT = (LV == 0) ? PP::GAGB : PP::SGB;
  __shared__ float sA[64 * 64];   // 16 KiB
  const int g    = blockIdx.x;
  const int lane = (int)(threadIdx.x & 63);
  const bool isB = lane < 16;
  const bool isA = (lane >= 16) && (lane < 24);
  const int bcol = lane & 15;
  const int acol = (lane - 16) & 7;

#pragma unroll 1
  for (int t = 0; t < 16; ++t)
    GLOAD_LDS16(ws + OFFAIN + (size_t)g * 4096u + t * 256 + lane * 4, sA + t * 256);

  float v[8];
#pragma unroll
  for (int m = 0; m < 8; ++m) v[m] = 0.f;
  if (isA) v[acol] = 1.f;

  float4 nb0, nb1;
  {
    const float* s = ws + OFFBIN + (size_t)(g * 64) * 128u + (size_t)bcol * 8u;
    nb0 = *(const float4*)s; nb1 = *(const float4*)(s + 4);
  }
  WAIT_VM(0);

#pragma unroll 1
  for (int j = 0; j < 64; ++j) {
    const int c = g * 64 + j;
    float bB[8] = {nb0.x, nb0.y, nb0.z, nb0.w, nb1.x, nb1.y, nb1.z, nb1.w};
    if (j + 1 < 64) {
      const float* s = ws + OFFBIN + (size_t)(c + 1) * 128u + (size_t)bcol * 8u;
      nb0 = *(const float4*)s; nb1 = *(const float4*)(s + 4);
    }
    if (isB) {
      float* dst = ws + OFFBIN + (size_t)c * 128u + (size_t)bcol * 8u;
#pragma unroll
      for (int m = 0; m < 8; ++m) dst[m] = v[m];
    } else if (isA) {
      float* dst = ws + OFFAIN + (size_t)c * 64u + (size_t)acol * 8u;
#pragma unroll
      for (int m = 0; m < 8; ++m) dst[m] = v[m];
    }
    const float* Aj = sA + j * 64;
    float nv[8];
#pragma unroll
    for (int m = 0; m < 8; ++m) nv[m] = 0.f;
#pragma unroll
    for (int t = 0; t < 8; ++t) {
      float4 col0 = *(const float4*)(Aj + t * 8);
      float4 col1 = *(const float4*)(Aj + t * 8 + 4);
      nv[0] += col0.x * v[t]; nv[1] += col0.y * v[t];
      nv[2] += col0.z * v[t]; nv[3] += col0.w * v[t];
      nv[4] += col1.x * v[t]; nv[5] += col1.y * v[t];
      nv[6] += col1.z * v[t]; nv[7] += col1.w * v[t];
    }
    if (isB) {
#pragma unroll
      for (int m = 0; m < 8; ++m) nv[m] += bB[m];
    }
#pragma unroll
    for (int m = 0; m < 8; ++m) v[m] = nv[m];
  }

  if (isB) {
    float* dst = ws + OFFBOUT + (size_t)g * 128u + (size_t)bcol * 8u;
#pragma unroll
    for (int m = 0; m < 8; ++m) dst[m] = v[m];
  } else if (isA) {
    float* dst = ws + OFFAOUT + (size_t)g * 64u + (size_t)acol * 8u;
#pragma unroll
    for (int m = 0; m < 8; ++m) dst[m] = v[m];
  }
}

// ---------- Phase 2c: single-wave scan over the NS super aggregates --------
// IN-PLACE on SGB: slot <- global-exclusive B prefix. SGA read-only.
template<int NC>
__global__ __launch_bounds__(64) void k2c_topscan(float* __restrict__ ws)
{
  using PP = P<NC>;
  const int lane = (int)(threadIdx.x & 63);
  const bool isB = lane < 16;
  const int bcol = lane & 15;

  float v[8];
#pragma unroll
  for (int m = 0; m < 8; ++m) v[m] = 0.f;

#pragma unroll 1
  for (int j = 0; j < PP::NS; ++j) {
    float bB[8];
    if (isB) {
      const float* s = ws + PP::SGB + (size_t)j * 128u + (size_t)bcol * 8u;
#pragma unroll
      for (int m = 0; m < 8; ++m) bB[m] = s[m];
      float* dst = ws + PP::SGB + (size_t)j * 128u + (size_t)bcol * 8u;
#pragma unroll
      for (int m = 0; m < 8; ++m) dst[m] = v[m];
    }
    const float* Aj = ws + PP::SGA + (size_t)j * 64u;
    float nv[8];
#pragma unroll
    for (int m = 0; m < 8; ++m) nv[m] = 0.f;
#pragma unroll
    for (int t = 0; t < 8; ++t) {
      float4 col0 = *(const float4*)(Aj + t * 8);
      float4 col1 = *(const float4*)(Aj + t * 8 + 4);
      nv[0] += col0.x * v[t]; nv[1] += col0.y * v[t];
      nv[2] += col0.z * v[t]; nv[3] += col0.w * v[t];
      nv[4] += col1.x * v[t]; nv[5] += col1.y * v[t];
      nv[6] += col1.z * v[t]; nv[7] += col1.w * v[t];
    }
    if (isB) {
#pragma unroll
      for (int m = 0; m < 8; ++m) nv[m] += bB[m];
    }
#pragma unroll
    for (int m = 0; m < 8; ++m) v[m] = nv[m];
  }
}

// ---------- Phase 3: replay each chunk from its carry, emit y --------------
// 4 chunks/wave, k = lane&15 = f column; all 64 lanes compute + store.
// f-init composes 3 levels: f0 = prefB_c + prefA_c@(gB_gr + gA_gr@sB_s).
// Buffer: a[2][4][64] | q @512 | p @576 | x @640. BUF=768, x3.
#define K3_COMP(E, FS, FD) do {                                              \
    const float xk_ = xgb[(E) * 16];                                         \
    const float4 q0_ = *(const float4*)(qgb + (E) * 8);                      \
    const float4 q1_ = *(const float4*)(qgb + (E) * 8 + 4);                  \
    const float4 p0_ = *(const float4*)(pgb + (E) * 8);                      \
    const float4 p1_ = *(const float4*)(pgb + (E) * 8 + 4);                  \
    const float y_ = p0_.x*FS[0] + p0_.y*FS[1] + p0_.z*FS[2] + p0_.w*FS[3]   \
                   + p1_.x*FS[4] + p1_.y*FS[5] + p1_.z*FS[6] + p1_.w*FS[7];  \
    const int i_ = c * CH + ss * 2 + (E);                                    \
    if (i_ < NTOT) out[(size_t)i_ * 16u + k] = y_;                           \
    const float qv_[8] = {q0_.x,q0_.y,q0_.z,q0_.w,q1_.x,q1_.y,q1_.z,q1_.w};  \
    _Pragma("unroll") for (int mm = 0; mm < 8; ++mm) {                       \
      const float4 r0_ = *(const float4*)(agb + (E) * 256 + mm * 8);         \
      const float4 r1_ = *(const float4*)(agb + (E) * 256 + mm * 8 + 4);     \
      FD[mm] = qv_[mm] * xk_                                                 \
             + r0_.x*FS[0] + r0_.y*FS[1] + r0_.z*FS[2] + r0_.w*FS[3]         \
             + r1_.x*FS[4] + r1_.y*FS[5] + r1_.z*FS[6] + r1_.w*FS[7];        \
    }                                                                        \
  } while (0)

template<int NC>
__global__ __launch_bounds__(256, 4) void k3_output(
    const float* __restrict__ p, const float* __restrict__ q,
    const float* __restrict__ a, const float* __restrict__ x,
    const float* __restrict__ ws, float* __restrict__ out)
{
  using PP = P<NC>;
  constexpr int CH = PP::CH, NST = PP::NST;
  __shared__ float sm3[4 * 3 * 768];  // 36864 B
  const int wv   = (int)(threadIdx.x >> 6);
  const int wave = blockIdx.x * 4 + wv;
  const int lane = (int)(threadIdx.x & 63);
  const int g    = lane >> 4;
  const int k    = lane & 15;
  const int c    = wave * 4 + g;
  const int gr   = c >> 6;
  const int sidx = gr >> 6;

  const int cb = wave * 4;
  float* b0 = sm3 + wv * 2304;
  float* b1 = b0 + 768;
  float* b2 = b0 + 1536;

  const int goff = g * 64;
  const int qoff = 512 + g * 16;
  const int poff = 576 + g * 16;
  const int xoff = 640 + (g >> 1) * 64 + (g & 1) * 32 + k;

  auto stage = [&](int ss, float* lb) {          // 6 loads
    const int base = cb * CH + ss * 2;
    GLOAD_LDS16(a + (size_t)iminc(base + (lane >> 4) * CH,     NTOT - 1) * 64u + (lane & 15) * 4, lb);
    GLOAD_LDS16(a + (size_t)iminc(base + (lane >> 4) * CH + 1, NTOT - 1) * 64u + (lane & 15) * 4, lb + 256);
    GLOAD_LDS4 (q + (size_t)iminc(base + (lane >> 4) * CH + ((lane >> 3) & 1), NTOT - 1) * 8u  + (lane & 7),  lb + 512);
    GLOAD_LDS4 (p + (size_t)iminc(base + (lane >> 4) * CH + ((lane >> 3) & 1), NTOT - 1) * 8u  + (lane & 7),  lb + 576);
    GLOAD_LDS4 (x + (size_t)iminc(base + (lane >> 5) * CH + ((lane >> 4) & 1), NTOT - 1) * 16u + (lane & 15), lb + 640);
    GLOAD_LDS4 (x + (size_t)iminc(base + (2 + (lane >> 5)) * CH + ((lane >> 4) & 1), NTOT - 1) * 16u + (lane & 15), lb + 704);
  };

  stage(0, b0);   // issue first; f-init hides under the loads
  stage(1, b1);

  // f-init: t1 = gB_gr[:,k] + gA_gr @ sB_s[:,k]; f0 = prefB_c[:,k] + prefA_c @ t1
  const float* __restrict__ sBc = ws + PP::SGB  + (size_t)sidx * 128u + (size_t)k * 8u;
  const float* __restrict__ gBc = ws + PP::GAGB + (size_t)gr   * 128u + (size_t)k * 8u;
  const float* __restrict__ gA  = ws + PP::GAGA + (size_t)gr   * 64u;
  const float* __restrict__ pA  = ws + PP::AGGA + (size_t)c    * 64u;
  const float* __restrict__ lBc = ws + PP::AGGB + (size_t)c    * 128u + (size_t)k * 8u;
  float t1[8];
#pragma unroll
  for (int m = 0; m < 8; ++m) t1[m] = gBc[m];
#pragma unroll
  for (int t = 0; t < 8; ++t) {
    float4 c0 = *(const float4*)(gA + t * 8);
    float4 c1 = *(const float4*)(gA + t * 8 + 4);
    const float st = sBc[t];
    t1[0] += c0.x * st; t1[1] += c0.y * st; t1[2] += c0.z * st; t1[3] += c0.w * st;
    t1[4] += c1.x * st; t1[5] += c1.y * st; t1[6] += c1.z * st; t1[7] += c1.w * st;
  }
  float f0[8], f1[8];
#pragma unroll
  for (int m = 0; m < 8; ++m) f0[m] = lBc[m];
#pragma unroll
  for (int t = 0; t < 8; ++t) {
    float4 c0 = *(const float4*)(pA + t * 8);
    float4 c1 = *(const float4*)(pA + t * 8 + 4);
    const float gt = t1[t];
    f0[0] += c0.x * gt; f0[1] += c0.y * gt; f0[2] += c0.z * gt; f0[3] += c0.w * gt;
    f0[4] += c1.x * gt; f0[5] += c1.y * gt; f0[6] += c1.z * gt; f0[7] += c1.w * gt;
  }

#pragma unroll 1
  for (int ss = 0; ss < NST; ++ss) {
    float* lb = b0;
    if (ss + 2 < NST) {
      stage(ss + 2, b2);
      WAIT_VM(12);
    } else if (ss + 1 < NST) {
      WAIT_VM(6);
    } else {
      WAIT_VM(0);
    }
    const float* agb = lb + goff;
    const float* qgb = lb + qoff;
    const float* pgb = lb + poff;
    const float* xgb = lb + xoff;
    K3_COMP(0, f0, f1);
    K3_COMP(1, f1, f0);
    float* t = b0; b0 = b1; b1 = b2; b2 = t;
  }
}

template<int NC>
static void launch_all(const float* p, const float* q, const float* a,
                       const float* x, float* out, float* ws, hipStream_t stream)
{
  using PP = P<NC>;
  hipLaunchKernelGGL(HIP_KERNEL_NAME(k1_aggregate<NC>), dim3(NC / 16), dim3(256), 0, stream, q, a, x, ws);
  hipLaunchKernelGGL(HIP_KERNEL_NAME(k2scan<NC, 0>),    dim3(PP::NG),  dim3(64),  0, stream, ws);
  hipLaunchKernelGGL(HIP_KERNEL_NAME(k2scan<NC, 1>),    dim3(PP::NS),  dim3(64),  0, stream, ws);
  hipLaunchKernelGGL(HIP_KERNEL_NAME(k2c_topscan<NC>),  dim3(1),       dim3(64),  0, stream, ws);
  hipLaunchKernelGGL(HIP_KERNEL_NAME(k3_output<NC>),    dim3(NC / 16), dim3(256), 0, stream, p, q, a, x, ws, out);
}

extern "C" void kernel_launch(void* const* d_in, const int* in_sizes, int n_in,
                              void* d_out, int out_size, void* d_ws, size_t ws_size,
                              hipStream_t stream)
{
  const float* p = (const float*)d_in[0];
  const float* q = (const float*)d_in[1];
  const float* a = (const float*)d_in[2];
  const float* x = (const float*)d_in[3];
  float* out = (float*)d_out;
  float* ws  = (float*)d_ws;

  if (ws_size >= P<16384>::BYTES) {
    launch_all<16384>(p, q, a, x, out, ws, stream);   // 4 waves/SIMD path
  } else {
    launch_all<8192>(p, q, a, x, out, ws, stream);    // fallback (fits 6.4 MB)
  }
}